// Round 4
// baseline (751.366 us; speedup 1.0000x reference)
//
#include <hip/hip_runtime.h>

#define W 64
#define D 256
#define NH 8

typedef unsigned short u16;
typedef __attribute__((ext_vector_type(8))) short bf16x8;
typedef __attribute__((ext_vector_type(4))) float f32x4;

__device__ __forceinline__ u16 f2bf(float f) {
    union { float f; unsigned u; } v; v.f = f;
    unsigned r = v.u + 0x7fffu + ((v.u >> 16) & 1u);
    return (u16)(r >> 16);
}

__device__ __forceinline__ bf16x8 cvt8(float4 a, float4 b) {
    bf16x8 r;
    r[0] = (short)f2bf(a.x); r[1] = (short)f2bf(a.y);
    r[2] = (short)f2bf(a.z); r[3] = (short)f2bf(a.w);
    r[4] = (short)f2bf(b.x); r[5] = (short)f2bf(b.y);
    r[6] = (short)f2bf(b.z); r[7] = (short)f2bf(b.w);
    return r;
}

// =================== Kernel A: QKV GEMM -> bf16 qkv workspace ===================
// grid = 4096 windows, 512 thr (8 waves). wave = (head-pair h2, rowhalf).
// LDS: per-wave transpose strip [32 tok][72] u16 -> coalesced global stores.
__global__ __launch_bounds__(512, 4) void qkv_gemm(
    const float* __restrict__ x, const float* __restrict__ bqkv,
    const u16* __restrict__ wqkvT, u16* __restrict__ qkv)
{
    __shared__ __align__(16) u16 strip[NH][32][72];   // 36864 B

    const int tid = threadIdx.x, lane = tid & 63, wv = tid >> 6;
    const int l15 = lane & 15, g = lane >> 4;
    const int h2 = wv >> 1, rowhalf = wv & 1;
    const int w = blockIdx.x;
    const float* xw = x + (size_t)w * (W * D);
    const f32x4 z4 = {0.f, 0.f, 0.f, 0.f};

    // A-fragments for this wave's 32 rows, direct from global f32 (L2-dedup'd)
    bf16x8 afr[2][8];
    #pragma unroll
    for (int rt = 0; rt < 2; ++rt)
        #pragma unroll
        for (int ks = 0; ks < 8; ++ks) {
            const float* p = xw + (rowhalf * 32 + 16 * rt + l15) * D + ks * 32 + g * 8;
            float4 a = *(const float4*)p;
            float4 b = *(const float4*)(p + 4);
            afr[rt][ks] = cvt8(a, b);
        }

    u16 (*st)[72] = strip[wv];
    #pragma unroll
    for (int mat = 0; mat < 3; ++mat) {
        #pragma unroll
        for (int ho = 0; ho < 2; ++ho) {
            #pragma unroll
            for (int ct = 0; ct < 2; ++ct) {
                const int n0 = mat * 256 + (h2 * 2 + ho) * 32 + ct * 16;
                const u16* brow = wqkvT + (size_t)(n0 + l15) * 256;
                f32x4 acc0 = z4, acc1 = z4;
                #pragma unroll
                for (int ks = 0; ks < 8; ++ks) {
                    bf16x8 bf = *(const bf16x8*)(brow + ks * 32 + g * 8);
                    acc0 = __builtin_amdgcn_mfma_f32_16x16x32_bf16(afr[0][ks], bf, acc0, 0, 0, 0);
                    acc1 = __builtin_amdgcn_mfma_f32_16x16x32_bf16(afr[1][ks], bf, acc1, 0, 0, 0);
                }
                const float bias = bqkv[n0 + l15];
                const int col = ho * 32 + ct * 16 + l15;
                #pragma unroll
                for (int r = 0; r < 4; ++r) {
                    st[     4 * g + r][col] = f2bf(acc0[r] + bias);
                    st[16 + 4 * g + r][col] = f2bf(acc1[r] + bias);
                }
            }
        }
        // strip -> qkv[(w*3+mat)][rowhalf*32 + tok][h2*64 + ...], coalesced b128
        #pragma unroll
        for (int it = 0; it < 4; ++it) {
            int idx = it * 64 + lane;          // 0..255
            int tokl = idx >> 3, chunk = idx & 7;
            bf16x8 vv = *(const bf16x8*)&st[tokl][chunk * 8];
            u16* dst = qkv + (((size_t)w * 3 + mat) * W + rowhalf * 32 + tokl) * D
                           + h2 * 64 + chunk * 8;
            *(bf16x8*)dst = vv;
        }
        asm volatile("s_waitcnt lgkmcnt(0)" ::: "memory");  // strip WAR before next mat
    }
}

// =================== Kernel B: attention + proj ===================
// grid = 4096 windows, 512 thr (8 waves), wave = head.
// LDS: ao [64][264] u16 (33792) + P [8][16][72] u16 (18432) = 52224 B.
__global__ __launch_bounds__(512, 4) void attn_proj(
    const u16* __restrict__ qkv, const float* __restrict__ relb,
    const float* __restrict__ bproj, const u16* __restrict__ wprojT,
    float* __restrict__ out)
{
    __shared__ __align__(16) char smem[52224];
    u16* ao = (u16*)smem;                       // [64][264]
    const int tid = threadIdx.x, lane = tid & 63, h = tid >> 6;
    const int l15 = lane & 15, g = lane >> 4;
    const int w = blockIdx.x;
    u16* Pb = (u16*)(smem + 33792) + h * 16 * 72;

    const u16* q = qkv + ((size_t)w * 3 + 0) * (W * D);
    const u16* k = qkv + ((size_t)w * 3 + 1) * (W * D);
    const u16* v = qkv + ((size_t)w * 3 + 2) * (W * D);
    const f32x4 z4 = {0.f, 0.f, 0.f, 0.f};

    // q/k fragments: direct bf16 loads (lane=token, d-contiguous)
    bf16x8 qf[4], kf[4];
    #pragma unroll
    for (int t = 0; t < 4; ++t) {
        qf[t] = *(const bf16x8*)(q + (16 * t + l15) * D + h * 32 + g * 8);
        kf[t] = *(const bf16x8*)(k + (16 * t + l15) * D + h * 32 + g * 8);
    }
    // v B-fragments: gather columns (full cache-line utilization across lanes)
    bf16x8 vf[2][2];
    #pragma unroll
    for (int ks = 0; ks < 2; ++ks)
        #pragma unroll
        for (int cd = 0; cd < 2; ++cd) {
            bf16x8 r;
            #pragma unroll
            for (int j = 0; j < 8; ++j)
                ((u16*)&r)[j] = v[(ks * 32 + g * 8 + j) * D + h * 32 + cd * 16 + l15];
            vf[ks][cd] = r;
        }

    const float* b2 = relb + h * 127;
    const float scale = 0.17677669529663687f;   // 1/sqrt(32)

    #pragma unroll
    for (int rt = 0; rt < 4; ++rt) {
        f32x4 s[4];
        #pragma unroll
        for (int ct = 0; ct < 4; ++ct)
            s[ct] = __builtin_amdgcn_mfma_f32_16x16x32_bf16(qf[rt], kf[ct], z4, 0, 0, 0);

        // no-max softmax: exp, store unnormalized E, accumulate row sums
        float psum[4] = {0.f, 0.f, 0.f, 0.f};
        #pragma unroll
        for (int ct = 0; ct < 4; ++ct) {
            const int ktok = 16 * ct + l15;
            #pragma unroll
            for (int r = 0; r < 4; ++r) {
                const int qtok = 16 * rt + 4 * g + r;
                float sv = s[ct][r] * scale + b2[ktok - qtok + 63];
                float ee = __expf(sv);
                psum[r] += ee;
                Pb[(4 * g + r) * 72 + ct * 16 + l15] = f2bf(ee);
            }
        }
        float inv[4];
        #pragma unroll
        for (int r = 0; r < 4; ++r) {
            float sum = psum[r];
            #pragma unroll
            for (int m = 1; m <= 8; m <<= 1)
                sum += __shfl_xor(sum, m, 64);
            inv[r] = 1.0f / sum;
        }
        bf16x8 pf0 = *(const bf16x8*)(Pb + l15 * 72 + g * 8);
        bf16x8 pf1 = *(const bf16x8*)(Pb + l15 * 72 + 32 + g * 8);
        #pragma unroll
        for (int cd = 0; cd < 2; ++cd) {
            f32x4 o = __builtin_amdgcn_mfma_f32_16x16x32_bf16(pf0, vf[0][cd], z4, 0, 0, 0);
            o = __builtin_amdgcn_mfma_f32_16x16x32_bf16(pf1, vf[1][cd], o, 0, 0, 0);
            #pragma unroll
            for (int r = 0; r < 4; ++r)
                ao[(16 * rt + 4 * g + r) * 264 + h * 32 + cd * 16 + l15] = f2bf(o[r] * inv[r]);
        }
    }
    __syncthreads();   // ao complete (cross-wave for proj)

    // proj: wave h -> cols h*32..+31, all 64 rows
    f32x4 pacc[2][4] = {{z4, z4, z4, z4}, {z4, z4, z4, z4}};
    const u16* brow0 = wprojT + (size_t)(h * 32 + l15) * 256;
    const u16* brow1 = wprojT + (size_t)(h * 32 + 16 + l15) * 256;
    #pragma unroll
    for (int ks = 0; ks < 8; ++ks) {
        bf16x8 b0 = *(const bf16x8*)(brow0 + ks * 32 + g * 8);
        bf16x8 b1 = *(const bf16x8*)(brow1 + ks * 32 + g * 8);
        #pragma unroll
        for (int rt = 0; rt < 4; ++rt) {
            bf16x8 a = *(const bf16x8*)(ao + (16 * rt + l15) * 264 + ks * 32 + g * 8);
            pacc[0][rt] = __builtin_amdgcn_mfma_f32_16x16x32_bf16(a, b0, pacc[0][rt], 0, 0, 0);
            pacc[1][rt] = __builtin_amdgcn_mfma_f32_16x16x32_bf16(a, b1, pacc[1][rt], 0, 0, 0);
        }
    }
    float* outw = out + (size_t)w * (W * D);
    #pragma unroll
    for (int ct = 0; ct < 2; ++ct) {
        const int n = h * 32 + ct * 16 + l15;
        const float bp = bproj[n];
        #pragma unroll
        for (int rt = 0; rt < 4; ++rt)
            #pragma unroll
            for (int r = 0; r < 4; ++r)
                outw[(16 * rt + 4 * g + r) * D + n] = pacc[ct][rt][r] + bp;
    }
}

// =================== Fallback fused kernel (R1, proven @468us) ===================
#define OFF_QK 0
#define QK_ROW 72
#define OFF_VT 73728
#define VT_ROW 72
#define OFF_P  110592
#define P_ROW  72
#define OFF_XS 129024
#define XS_ROW 264

__global__ __launch_bounds__(512, 2) void win_attn_fused(
    const float* __restrict__ x, const float* __restrict__ bqkv,
    const float* __restrict__ bproj, const float* __restrict__ relb,
    const u16* __restrict__ wqkvT, const u16* __restrict__ wprojT,
    float* __restrict__ out)
{
    __shared__ __align__(16) char smem[162816];
    const int tid = threadIdx.x, lane = tid & 63, wv = tid >> 6;
    const int l15 = lane & 15, g = lane >> 4, w = blockIdx.x;
    u16* qk = (u16*)(smem + OFF_QK);
    u16* vT = (u16*)(smem + OFF_VT);
    u16* Pb = (u16*)(smem + OFF_P) + wv * 16 * P_ROW;
    u16* xs = (u16*)(smem + OFF_XS);
    const f32x4 z4 = {0.f, 0.f, 0.f, 0.f};
    const float* xw = x + (size_t)w * (W * D);
    #pragma unroll
    for (int i = 0; i < 8; ++i) {
        int e = i * 2048 + tid * 4, row = e >> 8, col = e & 255;
        float4 v = *(const float4*)(xw + e);
        ushort4 b; b.x = f2bf(v.x); b.y = f2bf(v.y); b.z = f2bf(v.z); b.w = f2bf(v.w);
        *(ushort4*)(xs + row * XS_ROW + col) = b;
    }
    __syncthreads();
    bf16x8 afr[4][8];
    #pragma unroll
    for (int rt = 0; rt < 4; ++rt)
        #pragma unroll
        for (int ks = 0; ks < 8; ++ks)
            afr[rt][ks] = *(const bf16x8*)((const char*)smem + OFF_XS +
                           (16 * rt + l15) * (XS_ROW * 2) + ks * 64 + g * 16);
    __syncthreads();
    #pragma unroll
    for (int mc = 0; mc < 6; ++mc) {
        const int mat = mc >> 1, ct = mc & 1;
        const int n0 = mat * 256 + wv * 32 + ct * 16;
        const u16* brow = wqkvT + (size_t)(n0 + l15) * 256;
        f32x4 acc[4] = {z4, z4, z4, z4};
        #pragma unroll
        for (int ks = 0; ks < 8; ++ks) {
            bf16x8 bf = *(const bf16x8*)(brow + ks * 32 + g * 8);
            #pragma unroll
            for (int rt = 0; rt < 4; ++rt)
                acc[rt] = __builtin_amdgcn_mfma_f32_16x16x32_bf16(afr[rt][ks], bf, acc[rt], 0, 0, 0);
        }
        const float bias = bqkv[n0 + l15];
        if (mat < 2) {
            u16* dst = qk + wv * 64 * QK_ROW + mat * 32 + ct * 16 + l15;
            #pragma unroll
            for (int rt = 0; rt < 4; ++rt)
                #pragma unroll
                for (int r = 0; r < 4; ++r)
                    dst[(16 * rt + 4 * g + r) * QK_ROW] = f2bf(acc[rt][r] + bias);
        } else {
            u16* dst = vT + wv * 32 * VT_ROW + (ct * 16 + l15) * VT_ROW;
            #pragma unroll
            for (int rt = 0; rt < 4; ++rt)
                #pragma unroll
                for (int r = 0; r < 4; ++r)
                    dst[16 * rt + 4 * g + r] = f2bf(acc[rt][r] + bias);
        }
    }
    const u16* qbase = qk + wv * 64 * QK_ROW;
    bf16x8 qf[4], kf[4];
    #pragma unroll
    for (int t = 0; t < 4; ++t) {
        qf[t] = *(const bf16x8*)(qbase + (16 * t + l15) * QK_ROW + g * 8);
        kf[t] = *(const bf16x8*)(qbase + (16 * t + l15) * QK_ROW + 32 + g * 8);
    }
    bf16x8 vf[2][2];
    #pragma unroll
    for (int ks = 0; ks < 2; ++ks)
        #pragma unroll
        for (int cd = 0; cd < 2; ++cd)
            vf[ks][cd] = *(const bf16x8*)(vT + wv * 32 * VT_ROW + (16 * cd + l15) * VT_ROW + ks * 32 + g * 8);
    const float* biasrow = relb + wv * 127;
    const float scale = 0.17677669529663687f;
    u16* ao = xs;
    #pragma unroll
    for (int rt = 0; rt < 4; ++rt) {
        f32x4 s[4];
        #pragma unroll
        for (int ct = 0; ct < 4; ++ct)
            s[ct] = __builtin_amdgcn_mfma_f32_16x16x32_bf16(qf[rt], kf[ct], z4, 0, 0, 0);
        float sv[4][4];
        #pragma unroll
        for (int ct = 0; ct < 4; ++ct) {
            const int k_tok = 16 * ct + l15;
            #pragma unroll
            for (int r = 0; r < 4; ++r) {
                const int q_tok = 16 * rt + 4 * g + r;
                sv[ct][r] = s[ct][r] * scale + biasrow[k_tok - q_tok + 63];
            }
        }
        #pragma unroll
        for (int r = 0; r < 4; ++r) {
            float m = fmaxf(fmaxf(sv[0][r], sv[1][r]), fmaxf(sv[2][r], sv[3][r]));
            #pragma unroll
            for (int mask = 1; mask <= 8; mask <<= 1)
                m = fmaxf(m, __shfl_xor(m, mask, 64));
            float e0 = __expf(sv[0][r] - m), e1 = __expf(sv[1][r] - m);
            float e2 = __expf(sv[2][r] - m), e3 = __expf(sv[3][r] - m);
            float sum = (e0 + e1) + (e2 + e3);
            #pragma unroll
            for (int mask = 1; mask <= 8; mask <<= 1)
                sum += __shfl_xor(sum, mask, 64);
            const float inv = 1.0f / sum;
            const int prow = 4 * g + r;
            Pb[prow * P_ROW +      l15] = f2bf(e0 * inv);
            Pb[prow * P_ROW + 16 + l15] = f2bf(e1 * inv);
            Pb[prow * P_ROW + 32 + l15] = f2bf(e2 * inv);
            Pb[prow * P_ROW + 48 + l15] = f2bf(e3 * inv);
        }
        bf16x8 pf0 = *(const bf16x8*)(Pb + l15 * P_ROW + g * 8);
        bf16x8 pf1 = *(const bf16x8*)(Pb + l15 * P_ROW + 32 + g * 8);
        #pragma unroll
        for (int cd = 0; cd < 2; ++cd) {
            f32x4 o = __builtin_amdgcn_mfma_f32_16x16x32_bf16(pf0, vf[0][cd], z4, 0, 0, 0);
            o = __builtin_amdgcn_mfma_f32_16x16x32_bf16(pf1, vf[1][cd], o, 0, 0, 0);
            #pragma unroll
            for (int r = 0; r < 4; ++r)
                ao[(16 * rt + 4 * g + r) * XS_ROW + wv * 32 + 16 * cd + l15] = f2bf(o[r]);
        }
    }
    __syncthreads();
    bf16x8 pfr[4][8];
    #pragma unroll
    for (int rt = 0; rt < 4; ++rt)
        #pragma unroll
        for (int ks = 0; ks < 8; ++ks)
            pfr[rt][ks] = *(const bf16x8*)((const char*)smem + OFF_XS +
                           (16 * rt + l15) * (XS_ROW * 2) + ks * 64 + g * 16);
    f32x4 pacc[2][4] = {{z4, z4, z4, z4}, {z4, z4, z4, z4}};
    #pragma unroll
    for (int ct = 0; ct < 2; ++ct) {
        const u16* brow = wprojT + (size_t)(wv * 32 + ct * 16 + l15) * 256;
        #pragma unroll
        for (int ks = 0; ks < 8; ++ks) {
            bf16x8 bf = *(const bf16x8*)(brow + ks * 32 + g * 8);
            #pragma unroll
            for (int rt = 0; rt < 4; ++rt)
                pacc[ct][rt] = __builtin_amdgcn_mfma_f32_16x16x32_bf16(pfr[rt][ks], bf, pacc[ct][rt], 0, 0, 0);
        }
    }
    float* outw = out + (size_t)w * (W * D);
    #pragma unroll
    for (int ct = 0; ct < 2; ++ct) {
        const int n = wv * 32 + ct * 16 + l15;
        const float bp = bproj[n];
        #pragma unroll
        for (int rt = 0; rt < 4; ++rt)
            #pragma unroll
            for (int r = 0; r < 4; ++r)
                outw[(16 * rt + 4 * g + r) * D + n] = pacc[ct][rt][r] + bp;
    }
}

// Transpose + bf16-convert the weight matrices into workspace (L2-resident).
__global__ void prep_weights(const float* __restrict__ wqkv, const float* __restrict__ wproj,
                             u16* __restrict__ wqkvT, u16* __restrict__ wprojT)
{
    int i = blockIdx.x * 256 + threadIdx.x;
    if (i < 768 * 256) {
        int n = i >> 8, kk = i & 255;
        wqkvT[i] = f2bf(wqkv[kk * 768 + n]);
    } else {
        int j = i - 768 * 256;
        int n = j >> 8, kk = j & 255;
        wprojT[j] = f2bf(wproj[kk * 256 + n]);
    }
}

extern "C" void kernel_launch(void* const* d_in, const int* in_sizes, int n_in,
                              void* d_out, int out_size, void* d_ws, size_t ws_size,
                              hipStream_t stream)
{
    const float* x     = (const float*)d_in[0];
    const float* wqkv  = (const float*)d_in[1];
    const float* bqkv  = (const float*)d_in[2];
    const float* wproj = (const float*)d_in[3];
    const float* bproj = (const float*)d_in[4];
    const float* relb  = (const float*)d_in[5];

    u16* wqkvT  = (u16*)d_ws;                 // 768*256 u16 = 393216 B
    u16* wprojT = wqkvT + 768 * 256;          // 256*256 u16 -> ends at 524288 B

    prep_weights<<<1024, 256, 0, stream>>>(wqkv, wproj, wqkvT, wprojT);

    const int nwin = in_sizes[0] / (W * D);   // 4096
    const size_t qkv_off = 524288;
    const size_t need = qkv_off + (size_t)nwin * 3 * W * D * sizeof(u16);  // ~403 MB

    if (ws_size >= need) {
        u16* qkvws = (u16*)((char*)d_ws + qkv_off);
        qkv_gemm<<<nwin, 512, 0, stream>>>(x, bqkv, wqkvT, qkvws);
        attn_proj<<<nwin, 512, 0, stream>>>(qkvws, relb, bproj, wprojT, (float*)d_out);
    } else {
        win_attn_fused<<<nwin, 512, 0, stream>>>(x, bqkv, bproj, relb, wqkvT, wprojT, (float*)d_out);
    }
}

// Round 5
// 335.531 us; speedup vs baseline: 2.2393x; 2.2393x over previous
//
#include <hip/hip_runtime.h>

#define W 64
#define D 256
#define NH 8

typedef unsigned short u16;
typedef __attribute__((ext_vector_type(8))) short bf16x8;
typedef __attribute__((ext_vector_type(4))) float f32x4;

__device__ __forceinline__ u16 f2bf(float f) {
    union { float f; unsigned u; } v; v.f = f;
    unsigned r = v.u + 0x7fffu + ((v.u >> 16) & 1u);
    return (u16)(r >> 16);
}

// ---------------- LDS layout (bytes) ----------------
// xs  : [64][264] u16   x bf16 staging; dead after QKV; aliased by attn_out  33792
// buf : per-wave [16][136] u16 transposer (q -> k -> vT -> P, time-muxed)     4352 x 8
// total 68608  -> 2 blocks/CU
#define XS_ROW 264
#define BUF_ROW 136
#define OFF_BUF 33792

__global__ __launch_bounds__(512, 4) void win_attn2(
    const float* __restrict__ x, const float* __restrict__ bqkv,
    const float* __restrict__ bproj, const float* __restrict__ relb,
    const u16* __restrict__ wqkvT, const u16* __restrict__ wprojT,
    float* __restrict__ out)
{
    __shared__ __align__(16) char smem[68608];

    const int tid  = threadIdx.x;
    const int lane = tid & 63;
    const int h    = tid >> 6;      // wave index == head
    const int l15  = lane & 15;
    const int g    = lane >> 4;
    const int w    = blockIdx.x;

    u16* xs  = (u16*)smem;
    u16* buf = (u16*)(smem + OFF_BUF) + h * 16 * BUF_ROW;

    const f32x4 z4 = {0.f, 0.f, 0.f, 0.f};

    // ---------- Phase 0: stage x window -> LDS bf16 ----------
    const float* xw = x + (size_t)w * (W * D);
    #pragma unroll
    for (int i = 0; i < 8; ++i) {
        int e = i * 2048 + tid * 4;
        int row = e >> 8, col = e & 255;
        float4 v = *(const float4*)(xw + e);
        ushort4 b;
        b.x = f2bf(v.x); b.y = f2bf(v.y); b.z = f2bf(v.z); b.w = f2bf(v.w);
        *(ushort4*)(xs + row * XS_ROW + col) = b;
    }
    __syncthreads();

    // ---------- Phase 1: QKV for head h; fragments kept in registers ----------
    bf16x8 qf[4], kf[4], vf[2][2];

    #pragma unroll
    for (int mat = 0; mat < 3; ++mat) {
        f32x4 acc[2][4];
        #pragma unroll
        for (int ct = 0; ct < 2; ++ct)
            #pragma unroll
            for (int rt = 0; rt < 4; ++rt)
                acc[ct][rt] = z4;

        const u16* bp0 = wqkvT + (size_t)(mat * 256 + h * 32 + l15) * 256;
        const u16* bp1 = bp0 + 16 * 256;
        #pragma unroll
        for (int ks = 0; ks < 8; ++ks) {
            bf16x8 b0 = *(const bf16x8*)(bp0 + ks * 32 + g * 8);
            bf16x8 b1 = *(const bf16x8*)(bp1 + ks * 32 + g * 8);
            #pragma unroll
            for (int rt = 0; rt < 4; ++rt) {
                bf16x8 a = *(const bf16x8*)(xs + (16 * rt + l15) * XS_ROW + ks * 32 + g * 8);
                acc[0][rt] = __builtin_amdgcn_mfma_f32_16x16x32_bf16(a, b0, acc[0][rt], 0, 0, 0);
                acc[1][rt] = __builtin_amdgcn_mfma_f32_16x16x32_bf16(a, b1, acc[1][rt], 0, 0, 0);
            }
        }
        const float bias0 = bqkv[mat * 256 + h * 32 + l15];
        const float bias1 = bqkv[mat * 256 + h * 32 + 16 + l15];

        asm volatile("s_waitcnt lgkmcnt(0)" ::: "memory");   // WAR: prior buf reads done
        if (mat < 2) {
            // C-layout (lane=d col, row=4g+r) -> buf[tok_local][rt*32 + d]
            #pragma unroll
            for (int ct = 0; ct < 2; ++ct) {
                const float bias = ct ? bias1 : bias0;
                #pragma unroll
                for (int rt = 0; rt < 4; ++rt)
                    #pragma unroll
                    for (int r = 0; r < 4; ++r)
                        buf[(4 * g + r) * BUF_ROW + rt * 32 + ct * 16 + l15] =
                            f2bf(acc[ct][rt][r] + bias);
            }
            asm volatile("s_waitcnt lgkmcnt(0)" ::: "memory");
            #pragma unroll
            for (int rt = 0; rt < 4; ++rt) {
                bf16x8 fr = *(const bf16x8*)(buf + l15 * BUF_ROW + rt * 32 + g * 8);
                if (mat == 0) qf[rt] = fr; else kf[rt] = fr;
            }
        } else {
            // v transposed: buf[d_local l15][cd*72 + tok], packed b64 per (cd,rt)
            #pragma unroll
            for (int cd = 0; cd < 2; ++cd) {
                const float bias = cd ? bias1 : bias0;
                #pragma unroll
                for (int rt = 0; rt < 4; ++rt) {
                    ushort4 pk;
                    pk.x = f2bf(acc[cd][rt][0] + bias);
                    pk.y = f2bf(acc[cd][rt][1] + bias);
                    pk.z = f2bf(acc[cd][rt][2] + bias);
                    pk.w = f2bf(acc[cd][rt][3] + bias);
                    *(ushort4*)(buf + l15 * BUF_ROW + cd * 72 + 16 * rt + 4 * g) = pk;
                }
            }
            asm volatile("s_waitcnt lgkmcnt(0)" ::: "memory");
            #pragma unroll
            for (int ks = 0; ks < 2; ++ks)
                #pragma unroll
                for (int cd = 0; cd < 2; ++cd)
                    vf[ks][cd] = *(const bf16x8*)(buf + l15 * BUF_ROW + cd * 72 + ks * 32 + g * 8);
        }
        asm volatile("s_waitcnt lgkmcnt(0)" ::: "memory");
    }
    __syncthreads();   // all xs reads done -> ao may alias xs

    // ---------- Phase 2: attention (wave-private; P via buf) ----------
    const float* b2 = relb + h * 127;
    const float scale = 0.17677669529663687f;   // 1/sqrt(32)
    u16* ao = xs;

    #pragma unroll
    for (int rt = 0; rt < 4; ++rt) {
        f32x4 s[4];
        #pragma unroll
        for (int ct = 0; ct < 4; ++ct)
            s[ct] = __builtin_amdgcn_mfma_f32_16x16x32_bf16(qf[rt], kf[ct], z4, 0, 0, 0);

        asm volatile("s_waitcnt lgkmcnt(0)" ::: "memory");   // WAR: prev rt's pf reads done
        float psum[4] = {0.f, 0.f, 0.f, 0.f};
        #pragma unroll
        for (int ct = 0; ct < 4; ++ct) {
            const int ktok = 16 * ct + l15;
            #pragma unroll
            for (int r = 0; r < 4; ++r) {
                const int qtok = 16 * rt + 4 * g + r;
                float sv = s[ct][r] * scale + b2[ktok - qtok + 63];
                float ee = __expf(sv);
                psum[r] += ee;
                buf[(4 * g + r) * BUF_ROW + ct * 16 + l15] = f2bf(ee);
            }
        }
        float inv[4];
        #pragma unroll
        for (int r = 0; r < 4; ++r) {
            float sum = psum[r];
            #pragma unroll
            for (int m = 1; m <= 8; m <<= 1)
                sum += __shfl_xor(sum, m, 64);
            inv[r] = 1.0f / sum;
        }
        asm volatile("s_waitcnt lgkmcnt(0)" ::: "memory");
        bf16x8 pf0 = *(const bf16x8*)(buf + l15 * BUF_ROW + g * 8);
        bf16x8 pf1 = *(const bf16x8*)(buf + l15 * BUF_ROW + 32 + g * 8);
        #pragma unroll
        for (int cd = 0; cd < 2; ++cd) {
            f32x4 o = __builtin_amdgcn_mfma_f32_16x16x32_bf16(pf0, vf[0][cd], z4, 0, 0, 0);
            o = __builtin_amdgcn_mfma_f32_16x16x32_bf16(pf1, vf[1][cd], o, 0, 0, 0);
            #pragma unroll
            for (int r = 0; r < 4; ++r)
                ao[(16 * rt + 4 * g + r) * XS_ROW + h * 32 + cd * 16 + l15] = f2bf(o[r] * inv[r]);
        }
    }
    __syncthreads();   // ao complete (cross-wave input to proj)

    // ---------- Phase 3: output projection (wave h -> cols h*32..+31) ----------
    f32x4 pacc[2][4];
    #pragma unroll
    for (int ct = 0; ct < 2; ++ct)
        #pragma unroll
        for (int rt = 0; rt < 4; ++rt)
            pacc[ct][rt] = z4;

    const u16* pp0 = wprojT + (size_t)(h * 32 + l15) * 256;
    const u16* pp1 = pp0 + 16 * 256;
    #pragma unroll
    for (int ks = 0; ks < 8; ++ks) {
        bf16x8 b0 = *(const bf16x8*)(pp0 + ks * 32 + g * 8);
        bf16x8 b1 = *(const bf16x8*)(pp1 + ks * 32 + g * 8);
        #pragma unroll
        for (int rt = 0; rt < 4; ++rt) {
            bf16x8 a = *(const bf16x8*)(ao + (16 * rt + l15) * XS_ROW + ks * 32 + g * 8);
            pacc[0][rt] = __builtin_amdgcn_mfma_f32_16x16x32_bf16(a, b0, pacc[0][rt], 0, 0, 0);
            pacc[1][rt] = __builtin_amdgcn_mfma_f32_16x16x32_bf16(a, b1, pacc[1][rt], 0, 0, 0);
        }
    }
    float* outw = out + (size_t)w * (W * D);
    #pragma unroll
    for (int ct = 0; ct < 2; ++ct) {
        const int n = h * 32 + ct * 16 + l15;
        const float bp = bproj[n];
        #pragma unroll
        for (int rt = 0; rt < 4; ++rt)
            #pragma unroll
            for (int r = 0; r < 4; ++r)
                outw[(16 * rt + 4 * g + r) * D + n] = pacc[ct][rt][r] + bp;
    }
}

// Transpose + bf16-convert the weight matrices into workspace (L2-resident).
__global__ void prep_weights(const float* __restrict__ wqkv, const float* __restrict__ wproj,
                             u16* __restrict__ wqkvT, u16* __restrict__ wprojT)
{
    int i = blockIdx.x * 256 + threadIdx.x;
    if (i < 768 * 256) {
        int n = i >> 8, kk = i & 255;
        wqkvT[i] = f2bf(wqkv[kk * 768 + n]);
    } else {
        int j = i - 768 * 256;
        int n = j >> 8, kk = j & 255;
        wprojT[j] = f2bf(wproj[kk * 256 + n]);
    }
}

extern "C" void kernel_launch(void* const* d_in, const int* in_sizes, int n_in,
                              void* d_out, int out_size, void* d_ws, size_t ws_size,
                              hipStream_t stream)
{
    const float* x     = (const float*)d_in[0];
    const float* wqkv  = (const float*)d_in[1];
    const float* bqkv  = (const float*)d_in[2];
    const float* wproj = (const float*)d_in[3];
    const float* bproj = (const float*)d_in[4];
    const float* relb  = (const float*)d_in[5];

    u16* wqkvT  = (u16*)d_ws;                 // 768*256 u16
    u16* wprojT = wqkvT + 768 * 256;          // 256*256 u16

    prep_weights<<<1024, 256, 0, stream>>>(wqkv, wproj, wqkvT, wprojT);

    const int nwin = in_sizes[0] / (W * D);   // 4096
    win_attn2<<<nwin, 512, 0, stream>>>(x, bqkv, bproj, relb, wqkvT, wprojT, (float*)d_out);
}